// Round 2
// baseline (4802.128 us; speedup 1.0000x reference)
//
#include <hip/hip_runtime.h>
#include <hip/hip_bf16.h>
#include <math.h>

#define NTOK 4096
#define C_DIM 1024
#define NH 16
#define NKV 4
#define HD 64
#define E_N 8
#define FF 4096
#define WIN 256
#define TT 1024

// ---------------- rmsnorm: one block per row, 256 thr, float4 ----------------
__global__ __launch_bounds__(256)
void rmsnorm_kernel(const float* __restrict__ x, const float* __restrict__ w,
                    float* __restrict__ out) {
    int row = blockIdx.x;
    int tid = threadIdx.x;
    const float4* xr = (const float4*)(x + (size_t)row * C_DIM);
    float4 v = xr[tid];
    float ss = v.x * v.x + v.y * v.y + v.z * v.z + v.w * v.w;
#pragma unroll
    for (int off = 32; off > 0; off >>= 1) ss += __shfl_xor(ss, off);
    __shared__ float red[4];
    if ((tid & 63) == 0) red[tid >> 6] = ss;
    __syncthreads();
    float tot = (red[0] + red[1]) + (red[2] + red[3]);
    float inv = rsqrtf(tot * (1.0f / C_DIM) + 1e-6f);
    float4 wv = ((const float4*)w)[tid];
    float4 o;
    o.x = v.x * inv * wv.x;
    o.y = v.y * inv * wv.y;
    o.z = v.z * inv * wv.z;
    o.w = v.w * inv * wv.w;
    ((float4*)(out + (size_t)row * C_DIM))[tid] = o;
}

// ---------------- generic SGEMM C[M,N] = A[M,K]@B[K,N] (+res) (+C2 copy) ----
// 128x128 tile, BK=16, 256 threads, 8x8 microtile.
__global__ __launch_bounds__(256)
void sgemm_nn(const float* __restrict__ A, const float* __restrict__ Bm,
              float* __restrict__ Cm, const float* __restrict__ res,
              float* __restrict__ C2, int M, int N, int K) {
    int bm = blockIdx.y, bn = blockIdx.x;
    __shared__ float As[16][132];
    __shared__ float Bs[16][128];
    int tid = threadIdx.x;
    int ar = tid >> 1, ak = (tid & 1) * 8;
    const float* Ap = A + (size_t)(bm * 128 + ar) * K + ak;
    int bk = tid >> 5, bn4 = (tid & 31) * 4;
    const float* Bp = Bm + (size_t)bk * N + bn * 128 + bn4;
    int tm0 = (tid & 15) * 8, tn0 = (tid >> 4) * 8;
    float acc[8][8] = {{0.0f}};
    for (int kt = 0; kt < K; kt += 16) {
        float4 a0 = *(const float4*)Ap;
        float4 a1 = *(const float4*)(Ap + 4);
        float4 b0 = *(const float4*)Bp;
        float4 b1 = *(const float4*)(Bp + (size_t)8 * N);
        __syncthreads();
        As[ak + 0][ar] = a0.x; As[ak + 1][ar] = a0.y;
        As[ak + 2][ar] = a0.z; As[ak + 3][ar] = a0.w;
        As[ak + 4][ar] = a1.x; As[ak + 5][ar] = a1.y;
        As[ak + 6][ar] = a1.z; As[ak + 7][ar] = a1.w;
        *(float4*)&Bs[bk][bn4] = b0;
        *(float4*)&Bs[bk + 8][bn4] = b1;
        __syncthreads();
#pragma unroll
        for (int kk = 0; kk < 16; kk++) {
            float aa[8], bb[8];
            *(float4*)&aa[0] = *(const float4*)&As[kk][tm0];
            *(float4*)&aa[4] = *(const float4*)&As[kk][tm0 + 4];
            *(float4*)&bb[0] = *(const float4*)&Bs[kk][tn0];
            *(float4*)&bb[4] = *(const float4*)&Bs[kk][tn0 + 4];
#pragma unroll
            for (int i = 0; i < 8; i++)
#pragma unroll
                for (int j = 0; j < 8; j++)
                    acc[i][j] = fmaf(aa[i], bb[j], acc[i][j]);
        }
        Ap += 16;
        Bp += (size_t)16 * N;
    }
#pragma unroll
    for (int i = 0; i < 8; i++) {
        int row = bm * 128 + tm0 + i;
        float* cp = Cm + (size_t)row * N + bn * 128 + tn0;
        float4 o0 = make_float4(acc[i][0], acc[i][1], acc[i][2], acc[i][3]);
        float4 o1 = make_float4(acc[i][4], acc[i][5], acc[i][6], acc[i][7]);
        if (res) {
            const float* rp = res + (size_t)row * N + bn * 128 + tn0;
            float4 r0 = *(const float4*)rp;
            float4 r1 = *(const float4*)(rp + 4);
            o0.x += r0.x; o0.y += r0.y; o0.z += r0.z; o0.w += r0.w;
            o1.x += r1.x; o1.y += r1.y; o1.z += r1.z; o1.w += r1.w;
        }
        *(float4*)cp = o0;
        *(float4*)(cp + 4) = o1;
        if (C2) {
            float* c2 = C2 + (size_t)row * N + bn * 128 + tn0;
            *(float4*)c2 = o0;
            *(float4*)(c2 + 4) = o1;
        }
    }
}

// ---------------- RoPE in-place on [rows, nheads*64]; one thread per (row,h,pair)
__global__ void rope_kernel(float* __restrict__ X, int nheads, int total) {
    int idx = blockIdx.x * 256 + threadIdx.x;
    if (idx >= total) return;
    int d = idx & 31;
    int rest = idx >> 5;
    int hh = rest % nheads;
    int row = rest / nheads;
    int t = row & (TT - 1);
    float invf = __powf(10000.0f, -(float)d * (1.0f / 32.0f));
    float fr = (float)t * invf;
    float sn, cs;
    sincosf(fr, &sn, &cs);
    float* p = X + (size_t)row * (nheads * HD) + hh * HD + d;
    float a = p[0], b = p[32];
    p[0] = a * cs - b * sn;
    p[32] = b * cs + a * sn;
}

// ---------------- sliding-window causal attention; one wave per query --------
__global__ __launch_bounds__(256)
void attn_kernel(const float* __restrict__ q, const float* __restrict__ k,
                 const float* __restrict__ v, float* __restrict__ y) {
    int wid = blockIdx.x * 4 + (threadIdx.x >> 6);
    int lane = threadIdx.x & 63;
    int t = wid & (TT - 1);
    int bh = wid >> 10;           // b*NH + h
    int h = bh & (NH - 1);
    int b = bh >> 4;
    int kvh = h >> 2;             // NH/NKV = 4
    size_t qoff = ((size_t)(b * TT + t)) * C_DIM + h * HD + lane;
    float qd = q[qoff] * 0.125f;  // fold 1/sqrt(64) into q
    int j0 = t - (WIN - 1);
    if (j0 < 0) j0 = 0;
    const float* kp = k + ((size_t)(b * TT + j0)) * (NKV * HD) + kvh * HD + lane;
    const float* vp = v + ((size_t)(b * TT + j0)) * (NKV * HD) + kvh * HD + lane;
    float m = -1e30f, l = 0.0f, acc = 0.0f;
    for (int j = j0; j <= t; j++) {
        float s = qd * kp[0];
#pragma unroll
        for (int off = 32; off > 0; off >>= 1) s += __shfl_xor(s, off);
        float vd = vp[0];
        float mn = fmaxf(m, s);
        float co = __expf(m - mn);
        float p = __expf(s - mn);
        l = l * co + p;
        acc = acc * co + p * vd;
        m = mn;
        kp += NKV * HD;
        vp += NKV * HD;
    }
    y[qoff] = acc / l;
}

// ---------------- gate + routing: one wave per token ------------------------
__global__ __launch_bounds__(64)
void gate_kernel(const float* __restrict__ g, const float* __restrict__ gw,
                 int* __restrict__ cnt, int* __restrict__ elist,
                 float* __restrict__ wlist) {
    int tok = blockIdx.x;
    int lane = threadIdx.x;
    const float* gr = g + (size_t)tok * C_DIM;
    float acc[8] = {0, 0, 0, 0, 0, 0, 0, 0};
    for (int j = 0; j < 16; j++) {
        int kk = j * 64 + lane;
        float gv = gr[kk];
        const float* wr = gw + (size_t)kk * 8;
        float4 w0 = *(const float4*)wr;
        float4 w1 = *(const float4*)(wr + 4);
        acc[0] = fmaf(gv, w0.x, acc[0]);
        acc[1] = fmaf(gv, w0.y, acc[1]);
        acc[2] = fmaf(gv, w0.z, acc[2]);
        acc[3] = fmaf(gv, w0.w, acc[3]);
        acc[4] = fmaf(gv, w1.x, acc[4]);
        acc[5] = fmaf(gv, w1.y, acc[5]);
        acc[6] = fmaf(gv, w1.z, acc[6]);
        acc[7] = fmaf(gv, w1.w, acc[7]);
    }
#pragma unroll
    for (int e = 0; e < 8; e++)
#pragma unroll
        for (int off = 32; off > 0; off >>= 1) acc[e] += __shfl_xor(acc[e], off);
    if (lane == 0) {
        int i1 = 0;
        float l1 = acc[0];
#pragma unroll
        for (int e2 = 1; e2 < 8; e2++)
            if (acc[e2] > l1) { l1 = acc[e2]; i1 = e2; }
        int i2 = -1;
        float l2 = -1e30f;
#pragma unroll
        for (int e2 = 0; e2 < 8; e2++)
            if (e2 != i1 && acc[e2] > l2) { l2 = acc[e2]; i2 = e2; }
        // normalized top-2 weights == softmax over {l1,l2}
        float wA = 1.0f / (1.0f + expf(l2 - l1));
        float wB = 1.0f - wA;
        int p1 = atomicAdd(&cnt[i1], 1);
        elist[i1 * NTOK + p1] = tok;
        wlist[i1 * NTOK + p1] = wA;
        int p2 = atomicAdd(&cnt[i2], 1);
        elist[i2 * NTOK + p2] = tok;
        wlist[i2 * NTOK + p2] = wB;
    }
}

__global__ void zero_cnt(int* __restrict__ cnt) {
    if (threadIdx.x < E_N) cnt[threadIdx.x] = 0;
}

// map global row-tile gy -> (expert e, local tile lt) using per-expert counts
__device__ __forceinline__ int map_tile(const int* __restrict__ cnt, int gy,
                                        int* lt_out) {
    int a = 0;
    for (int i = 0; i < E_N; i++) {
        int nt = (cnt[i] + 127) >> 7;
        if (gy < a + nt) { *lt_out = gy - a; return i; }
        a += nt;
    }
    return -1;
}

// ---------------- batched expert up-proj: hid = silu(g@W1) * (g@W3) ---------
// block tile: 128 rows x 64 cols (of FF), dual-B GEMM, gathered A rows
__global__ __launch_bounds__(256)
void moe_up_kernel(const float* __restrict__ g, const float* __restrict__ w1,
                   const float* __restrict__ w3, const int* __restrict__ cnt,
                   const int* __restrict__ elist, float* __restrict__ hid) {
    int gy = blockIdx.y;
    int lt;
    int e = map_tile(cnt, gy, &lt);
    if (e < 0) return;
    int cl = cnt[e];
    const float* W1 = w1 + (size_t)e * C_DIM * FF;
    const float* W3 = w3 + (size_t)e * C_DIM * FF;
    const int* el = elist + e * NTOK;
    int bn = blockIdx.x;
    __shared__ float As[16][132];
    __shared__ float B1s[16][64];
    __shared__ float B3s[16][64];
    int tid = threadIdx.x;
    int ar = tid >> 1, ak = (tid & 1) * 8;
    int la = lt * 128 + ar;
    bool av = la < cl;
    int tok = av ? el[la] : 0;
    const float* Ap = g + (size_t)tok * C_DIM + ak;
    int bkr = tid >> 4, bn4 = (tid & 15) * 4;
    const float* B1p = W1 + (size_t)bkr * FF + bn * 64 + bn4;
    const float* B3p = W3 + (size_t)bkr * FF + bn * 64 + bn4;
    int tm0 = (tid & 15) * 8, tn0 = (tid >> 4) * 4;
    float acc1[8][4] = {{0.0f}}, acc3[8][4] = {{0.0f}};
    for (int kt = 0; kt < C_DIM; kt += 16) {
        float4 a0, a1;
        if (av) {
            a0 = *(const float4*)Ap;
            a1 = *(const float4*)(Ap + 4);
        } else {
            a0 = make_float4(0, 0, 0, 0);
            a1 = make_float4(0, 0, 0, 0);
        }
        float4 b1 = *(const float4*)B1p;
        float4 b3 = *(const float4*)B3p;
        __syncthreads();
        As[ak + 0][ar] = a0.x; As[ak + 1][ar] = a0.y;
        As[ak + 2][ar] = a0.z; As[ak + 3][ar] = a0.w;
        As[ak + 4][ar] = a1.x; As[ak + 5][ar] = a1.y;
        As[ak + 6][ar] = a1.z; As[ak + 7][ar] = a1.w;
        *(float4*)&B1s[bkr][bn4] = b1;
        *(float4*)&B3s[bkr][bn4] = b3;
        __syncthreads();
#pragma unroll
        for (int kk = 0; kk < 16; kk++) {
            float aa[8];
            *(float4*)&aa[0] = *(const float4*)&As[kk][tm0];
            *(float4*)&aa[4] = *(const float4*)&As[kk][tm0 + 4];
            float bb1[4], bb3[4];
            *(float4*)&bb1[0] = *(const float4*)&B1s[kk][tn0];
            *(float4*)&bb3[0] = *(const float4*)&B3s[kk][tn0];
#pragma unroll
            for (int i = 0; i < 8; i++)
#pragma unroll
                for (int jj = 0; jj < 4; jj++) {
                    acc1[i][jj] = fmaf(aa[i], bb1[jj], acc1[i][jj]);
                    acc3[i][jj] = fmaf(aa[i], bb3[jj], acc3[i][jj]);
                }
        }
        Ap += 16;
        B1p += (size_t)16 * FF;
        B3p += (size_t)16 * FF;
    }
#pragma unroll
    for (int i = 0; i < 8; i++) {
        int lr = lt * 128 + tm0 + i;
        if (lr >= cl) continue;
        float o[4];
#pragma unroll
        for (int jj = 0; jj < 4; jj++) {
            float c1 = acc1[i][jj];
            float sg = c1 / (1.0f + __expf(-c1));  // silu
            o[jj] = sg * acc3[i][jj];
        }
        float* hp = hid + (size_t)(gy * 128 + tm0 + i) * FF + bn * 64 + tn0;
        *(float4*)hp = *(float4*)&o[0];
    }
}

// ---------------- batched expert down-proj: out[tok] += w * (hid @ W2) ------
// NOTE: each token appears in TWO expert lists (TOPK=2), so two blocks can
// concurrently update the same out[tok] range -> accumulation MUST be atomic.
__global__ __launch_bounds__(256)
void moe_down_kernel(const float* __restrict__ hid, const float* __restrict__ w2,
                     const int* __restrict__ cnt, const int* __restrict__ elist,
                     const float* __restrict__ wlist, float* __restrict__ out) {
    int gy = blockIdx.y;
    int lt;
    int e = map_tile(cnt, gy, &lt);
    if (e < 0) return;
    int cl = cnt[e];
    const float* W2 = w2 + (size_t)e * FF * C_DIM;
    const int* el = elist + e * NTOK;
    const float* wl = wlist + e * NTOK;
    int bn = blockIdx.x;
    __shared__ float As[16][132];
    __shared__ float Bs[16][128];
    int tid = threadIdx.x;
    int ar = tid >> 1, ak = (tid & 1) * 8;
    int la = lt * 128 + ar;
    bool av = la < cl;
    const float* Ap = hid + (size_t)(gy * 128 + ar) * FF + ak;
    int bk = tid >> 5, bn4 = (tid & 31) * 4;
    const float* Bp = W2 + (size_t)bk * C_DIM + bn * 128 + bn4;
    int tm0 = (tid & 15) * 8, tn0 = (tid >> 4) * 8;
    float acc[8][8] = {{0.0f}};
    for (int kt = 0; kt < FF; kt += 16) {
        float4 a0, a1;
        if (av) {
            a0 = *(const float4*)Ap;
            a1 = *(const float4*)(Ap + 4);
        } else {
            a0 = make_float4(0, 0, 0, 0);
            a1 = make_float4(0, 0, 0, 0);
        }
        float4 b0 = *(const float4*)Bp;
        float4 b1 = *(const float4*)(Bp + (size_t)8 * C_DIM);
        __syncthreads();
        As[ak + 0][ar] = a0.x; As[ak + 1][ar] = a0.y;
        As[ak + 2][ar] = a0.z; As[ak + 3][ar] = a0.w;
        As[ak + 4][ar] = a1.x; As[ak + 5][ar] = a1.y;
        As[ak + 6][ar] = a1.z; As[ak + 7][ar] = a1.w;
        *(float4*)&Bs[bk][bn4] = b0;
        *(float4*)&Bs[bk + 8][bn4] = b1;
        __syncthreads();
#pragma unroll
        for (int kk = 0; kk < 16; kk++) {
            float aa[8], bb[8];
            *(float4*)&aa[0] = *(const float4*)&As[kk][tm0];
            *(float4*)&aa[4] = *(const float4*)&As[kk][tm0 + 4];
            *(float4*)&bb[0] = *(const float4*)&Bs[kk][tn0];
            *(float4*)&bb[4] = *(const float4*)&Bs[kk][tn0 + 4];
#pragma unroll
            for (int i = 0; i < 8; i++)
#pragma unroll
                for (int j = 0; j < 8; j++)
                    acc[i][j] = fmaf(aa[i], bb[j], acc[i][j]);
        }
        Ap += 16;
        Bp += (size_t)16 * C_DIM;
    }
#pragma unroll
    for (int i = 0; i < 8; i++) {
        int lr = lt * 128 + tm0 + i;
        if (lr >= cl) continue;
        int tok = el[lr];
        float w = wl[lr];
        float* op = out + (size_t)tok * C_DIM + bn * 128 + tn0;
#pragma unroll
        for (int j = 0; j < 8; j++)
            atomicAdd(op + j, w * acc[i][j]);
    }
}

extern "C" void kernel_launch(void* const* d_in, const int* in_sizes, int n_in,
                              void* d_out, int out_size, void* d_ws, size_t ws_size,
                              hipStream_t stream) {
    const float* x = (const float*)d_in[0];
    const float* anw = (const float*)d_in[1];
    const float* fnw = (const float*)d_in[2];
    const float* wq = (const float*)d_in[3];
    const float* wk = (const float*)d_in[4];
    const float* wv = (const float*)d_in[5];
    const float* wo = (const float*)d_in[6];
    const float* gw = (const float*)d_in[7];
    const float* w1 = (const float*)d_in[8];
    const float* w2 = (const float*)d_in[9];
    const float* w3 = (const float*)d_in[10];
    float* out = (float*)d_out;
    float* ws = (float*)d_ws;

    // workspace layout (floats); total ~51.8M floats ~= 207 MB
    size_t off = 0;
    float* buf0 = ws + off; off += (size_t)NTOK * C_DIM;   // h_norm, later y
    float* buf1 = ws + off; off += (size_t)NTOK * C_DIM;   // q, later g
    float* kb = ws + off;   off += (size_t)NTOK * NKV * HD;
    float* vb = ws + off;   off += (size_t)NTOK * NKV * HD;
    float* hbuf = ws + off; off += (size_t)NTOK * C_DIM;   // h = x + attn_out@wo
    float* hid = ws + off;  off += (size_t)72 * 128 * FF;  // padded expert rows
    int* cnt = (int*)(ws + off);   off += E_N;
    int* elist = (int*)(ws + off); off += (size_t)E_N * NTOK;
    float* wlist = ws + off;       off += (size_t)E_N * NTOK;

    // ---- attention sub-block ----
    rmsnorm_kernel<<<NTOK, 256, 0, stream>>>(x, anw, buf0);
    sgemm_nn<<<dim3(8, 32), 256, 0, stream>>>(buf0, wq, buf1, nullptr, nullptr,
                                              NTOK, 1024, 1024);
    sgemm_nn<<<dim3(2, 32), 256, 0, stream>>>(buf0, wk, kb, nullptr, nullptr,
                                              NTOK, 256, 1024);
    sgemm_nn<<<dim3(2, 32), 256, 0, stream>>>(buf0, wv, vb, nullptr, nullptr,
                                              NTOK, 256, 1024);
    rope_kernel<<<(NTOK * NH * 32 + 255) / 256, 256, 0, stream>>>(buf1, NH,
                                                                  NTOK * NH * 32);
    rope_kernel<<<(NTOK * NKV * 32 + 255) / 256, 256, 0, stream>>>(kb, NKV,
                                                                   NTOK * NKV * 32);
    attn_kernel<<<NTOK * NH / 4, 256, 0, stream>>>(buf1, kb, vb, buf0);  // y -> buf0
    // h = x + y@wo ; also write h into d_out (MoE accumulates on top)
    sgemm_nn<<<dim3(8, 32), 256, 0, stream>>>(buf0, wo, hbuf, x, out,
                                              NTOK, 1024, 1024);

    // ---- MoE sub-block ----
    rmsnorm_kernel<<<NTOK, 256, 0, stream>>>(hbuf, fnw, buf1);  // g -> buf1
    zero_cnt<<<1, 64, 0, stream>>>(cnt);
    gate_kernel<<<NTOK, 64, 0, stream>>>(buf1, gw, cnt, elist, wlist);
    moe_up_kernel<<<dim3(FF / 64, 72), 256, 0, stream>>>(buf1, w1, w3, cnt, elist,
                                                         hid);
    moe_down_kernel<<<dim3(C_DIM / 128, 72), 256, 0, stream>>>(hid, w2, cnt, elist,
                                                               wlist, out);
}